// Round 5
// baseline (13917.467 us; speedup 1.0000x reference)
//
#include <hip/hip_runtime.h>
#include <cstdint>
#include <cstddef>

#define MINN 1e-15f
#define EPSA 1e-7f

typedef _Float16 half_t;
typedef _Float16 half2_t __attribute__((ext_vector_type(2)));

// ---------- device helpers ----------
__device__ __forceinline__ float tan_k_(float u, float sk) {
    float a = fminf(fmaxf(sk * u, -15.f), 15.f);
    return tanhf(a) / sk;
}
__device__ __forceinline__ float artan_k_(float u, float sk) {
    float a = fminf(fmaxf(sk * u, -1.f + EPSA), 1.f - EPSA);
    return atanhf(a) / sk;
}
__device__ __forceinline__ float wave_sum(float v) {
#pragma unroll
    for (int off = 32; off; off >>= 1) v += __shfl_xor(v, off, 64);
    return v;
}
// f16 pair dot-accumulate: acc += a.h0*b.h0 + a.h1*b.h1 (f32 accum)
__device__ __forceinline__ float dot2acc(uint32_t w, uint32_t h, float acc) {
#if defined(__has_builtin) && __has_builtin(__builtin_amdgcn_fdot2)
    return __builtin_amdgcn_fdot2(__builtin_bit_cast(half2_t, w),
                                  __builtin_bit_cast(half2_t, h), acc, false);
#else
    half2_t a = __builtin_bit_cast(half2_t, w);
    half2_t b = __builtin_bit_cast(half2_t, h);
    acc = fmaf((float)a[0], (float)b[0], acc);
    return fmaf((float)a[1], (float)b[1], acc);
#endif
}
// block(512)-wide reduce of N values, broadcast. Double-buffered caller
// scratch: exactly ONE internal barrier (caller guarantees buffer parity
// alternation between consecutive calls / intervening barriers).
template <int N>
__device__ __forceinline__ void bredDB(float* v, float* redbuf, int tid) {
#pragma unroll
    for (int n = 0; n < N; ++n) {
#pragma unroll
        for (int off = 32; off; off >>= 1) v[n] += __shfl_xor(v[n], off, 64);
    }
    int wave = tid >> 6, lane = tid & 63;
#pragma unroll
    for (int n = 0; n < N; ++n)
        if (lane == n) redbuf[n * 8 + wave] = v[n];
    __syncthreads();
#pragma unroll
    for (int n = 0; n < N; ++n) {
        float4 a = *(float4*)&redbuf[n * 8];
        float4 b = *(float4*)&redbuf[n * 8 + 4];
        v[n] = ((a.x + a.y) + (a.z + a.w)) + ((b.x + b.y) + (b.z + b.w));
    }
}

// ---------- K1: transpose 2 ih weight matrices [768x256] -> [256x768] ----------
__global__ __launch_bounds__(256) void kt_transpose(
    const float* __restrict__ a0, const float* __restrict__ a1,
    float* __restrict__ o0, float* __restrict__ o1) {
    int idx = blockIdx.x * 256 + threadIdx.x;
    int m = idx / 196608, rem = idx % 196608;
    int j = rem >> 8, kk = rem & 255;
    const float* in = (m == 0) ? a0 : a1;
    float* outp     = (m == 0) ? o0 : o1;
    outp[kk * 768 + j] = in[j * 256 + kk];
}

// ---------- prep1: pack stage-1 (W_hr,W_hz) f16 per-thread fragments ----------
// PAIR layout: thread t (p=t>>1, ph=t&1) owns output j=p for gates r,z over
// i in [ph*128, ph*128+128). Register m in [0,128): g=m>>6 (0=r,1=z),
// mi=m&63, i=ph*128+2*mi. Stored for uint4-coalesced loads:
// u32 index e = (m>>2)*2048 + t*4 + (m&3).
__global__ __launch_bounds__(256) void kt_prep1(
    const float* __restrict__ whh0, const float* __restrict__ whh1,
    uint32_t* __restrict__ p0, uint32_t* __restrict__ p1) {
    int idx = blockIdx.x * 256 + threadIdx.x;  // 131072
    int l = idx >> 16, e = idx & 65535;
    int r4 = e >> 11, rem = e & 2047;
    int t = rem >> 2, m = r4 * 4 + (rem & 3);
    int p = t >> 1, ph = t & 1;
    int g = m >> 6, mi = m & 63;
    int row = g ? (512 + p) : p;
    int i = ph * 128 + 2 * mi;
    const float* w = l ? whh1 : whh0;
    half2_t hv;
    hv[0] = (half_t)w[row * 256 + i];
    hv[1] = (half_t)w[row * 256 + i + 1];
    (l ? p1 : p0)[e] = __builtin_bit_cast(uint32_t, hv);
}

// ---------- prep2: pack stage-2 (W_hh_) f16 [i2][j] half2 ----------
__global__ __launch_bounds__(256) void kt_prep2(
    const float* __restrict__ whh0, const float* __restrict__ whh1,
    uint32_t* __restrict__ p0, uint32_t* __restrict__ p1) {
    int idx = blockIdx.x * 256 + threadIdx.x;  // 65536
    int l = idx >> 15, e = idx & 32767;
    int i2 = e >> 8, j = e & 255;
    const float* w = l ? whh1 : whh0;
    half2_t hv;
    hv[0] = (half_t)w[(256 + j) * 256 + 2 * i2];
    hv[1] = (half_t)w[(256 + j) * 256 + 2 * i2 + 1];
    (l ? p1 : p0)[e] = __builtin_bit_cast(uint32_t, hv);
}

// ---------- init / final ----------
__global__ __launch_bounds__(256) void kt_init(
    const float* __restrict__ h0, float* __restrict__ hcar) {
    int i = blockIdx.x * 256 + threadIdx.x;
    hcar[i] = h0[i];
}
__global__ __launch_bounds__(256) void kt_final(
    const float* __restrict__ hcar, float* __restrict__ dst) {
    int i = blockIdx.x * 256 + threadIdx.x;
    dst[i] = hcar[i];
}

// ---------- rowscale / gemm / mscale ----------
__global__ __launch_bounds__(256) void kt_rowscale(
    const float* __restrict__ src, long long strideB,
    float* __restrict__ s_arr, float* __restrict__ ax_arr,
    const float* __restrict__ kptr, int mode) {
    int lane = threadIdx.x & 63;
    int r = blockIdx.x * 4 + (threadIdx.x >> 6);
    float k = kptr[0], sk = sqrtf(-k);
    size_t off = (size_t)(r >> 6) * strideB + (size_t)(r & 63) * 256 + lane * 4;
    float4 v = *(const float4*)&src[off];
    float n2 = wave_sum(v.x * v.x + v.y * v.y + v.z * v.z + v.w * v.w);
    float n = sqrtf(n2);
    float s, xn;
    if (mode == 0) {
        float nrm = fmaxf(n, MINN);
        float tk = tan_k_(nrm, sk);
        s = tk / nrm;
        xn = fmaxf(tk * (n / nrm), MINN);
    } else {
        s = 1.f;
        xn = fmaxf(n, MINN);
    }
    float ax = artan_k_(xn, sk) / xn;
    if (lane == 0) { s_arr[r] = s; ax_arr[r] = ax; }
}

__global__ __launch_bounds__(256) void kt_gemm(
    const float* __restrict__ A, long long strideB,
    const float* __restrict__ s_arr,
    const float* __restrict__ Bt, float* __restrict__ C) {
    __shared__ float As[16][68];
    __shared__ float Bs[16][68];
    __shared__ float sS[64];
    int tid = threadIdx.x;
    int row0 = blockIdx.y * 64, col0 = blockIdx.x * 64;
    if (tid < 64) sS[tid] = s_arr[row0 + tid];
    int ty = tid >> 4, tx = tid & 15;
    int ra = tid >> 2, kq = tid & 3;
    int kb = tid >> 4, cq = tid & 15;
    float acc[4][4] = {};
    __syncthreads();
#pragma unroll 1
    for (int kt = 0; kt < 16; ++kt) {
        int k0 = kt * 16;
        int rc = row0 + ra;
        size_t aoff = (size_t)(rc >> 6) * strideB + (size_t)(rc & 63) * 256 + k0 + kq * 4;
        float4 av = *(const float4*)&A[aoff];
        float sc = sS[ra];
        float4 bv = *(const float4*)&Bt[(size_t)(k0 + kb) * 768 + col0 + cq * 4];
        As[kq * 4 + 0][ra] = av.x * sc;
        As[kq * 4 + 1][ra] = av.y * sc;
        As[kq * 4 + 2][ra] = av.z * sc;
        As[kq * 4 + 3][ra] = av.w * sc;
        *(float4*)&Bs[kb][cq * 4] = bv;
        __syncthreads();
#pragma unroll
        for (int kk = 0; kk < 16; ++kk) {
            float4 a4 = *(const float4*)&As[kk][ty * 4];
            float4 b4 = *(const float4*)&Bs[kk][tx * 4];
            float aa[4] = {a4.x, a4.y, a4.z, a4.w};
            float bb[4] = {b4.x, b4.y, b4.z, b4.w};
#pragma unroll
            for (int i = 0; i < 4; ++i)
#pragma unroll
                for (int j = 0; j < 4; ++j)
                    acc[i][j] = fmaf(aa[i], bb[j], acc[i][j]);
        }
        __syncthreads();
    }
#pragma unroll
    for (int i = 0; i < 4; ++i) {
        size_t row = (size_t)row0 + ty * 4 + i;
        *(float4*)&C[row * 768 + col0 + tx * 4] =
            make_float4(acc[i][0], acc[i][1], acc[i][2], acc[i][3]);
    }
}

__global__ __launch_bounds__(256) void kt_mscale(
    float* __restrict__ mx, const float* __restrict__ ax_arr,
    float* __restrict__ uxn, const float* __restrict__ kptr) {
    int lane = threadIdx.x & 63;
    int p = blockIdx.x * 4 + (threadIdx.x >> 6);
    int r = p / 3;
    int g = p - r * 3;
    float k = kptr[0], sk = sqrtf(-k);
    float* ptr = mx + (size_t)r * 768 + g * 256 + lane * 4;
    float4 v = *(const float4*)ptr;
    float n2 = wave_sum(v.x * v.x + v.y * v.y + v.z * v.z + v.w * v.w);
    float nt = sqrtf(n2);
    float mxn = fmaxf(nt, MINN);
    float arg = mxn * ax_arr[r];
    float tk = tan_k_(arg, sk);
    float f = tk / mxn;
    v.x *= f; v.y *= f; v.z *= f; v.w *= f;
    *(float4*)ptr = v;
    if (lane == 0) uxn[p] = tk * (nt / mxn);
}

// ---------- K6: persistent-weight scan, dual-role, PAIR layout ----------
// Thread t: p = t>>1 (output index j), ph = t&1 (i-half). Each pair
// computes one j; partials combine via shfl_xor(1). All block sums are
// duplicated per pair -> scale by 0.5 after bredDB.
__global__ __launch_bounds__(512, 1) void kt_scan2(
    const float* __restrict__ Ux_0, const float* __restrict__ uxn_0,
    const uint32_t* __restrict__ w1pk_0, const uint32_t* __restrict__ whh2g_0,
    const float* __restrict__ bias_0, float* __restrict__ hcar_0,
    float* __restrict__ out_0, long long sb_0, long long st_0,
    const float* __restrict__ Ux_1, const float* __restrict__ uxn_1,
    const uint32_t* __restrict__ w1pk_1, const uint32_t* __restrict__ whh2g_1,
    const float* __restrict__ bias_1, float* __restrict__ hcar_1,
    float* __restrict__ out_1, long long sb_1, long long st_1,
    const float* __restrict__ kptr, int Tc, int nrole0) {
    __shared__ uint4 whhS[8192];       // 128 KiB: W_hh_ f16, [i2-quad][j]
    __shared__ uint32_t hy2S[128];     // hy as 128 half2
    __shared__ uint32_t rh2S[128];     // rh as 128 half2
    __shared__ float redbuf[2][96];    // double-buffered bred scratch

    const int tid = threadIdx.x;
    const int role = (blockIdx.x >= nrole0) ? 1 : 0;
    const int bb = role ? (int)blockIdx.x - nrole0 : (int)blockIdx.x;

    const float* Ux      = role ? Ux_1 : Ux_0;
    const float* uxn     = role ? uxn_1 : uxn_0;
    const uint32_t* w1pk = role ? w1pk_1 : w1pk_0;
    const uint32_t* whh2g= role ? whh2g_1 : whh2g_0;
    const float* bias    = role ? bias_1 : bias_0;
    float* hcar          = role ? hcar_1 : hcar_0;
    float* outbase       = role ? out_1 : out_0;
    const long long stride_b = role ? sb_1 : sb_0;
    const long long stride_t = role ? st_1 : st_0;

    const int p = tid >> 1, ph = tid & 1;
    const float k = kptr[0], sk = sqrtf(-k);

    // stage-2 weights -> LDS
    for (int idx = tid; idx < 32768; idx += 512) {
        uint32_t v = whh2g[idx];
        int i2 = idx >> 8, col = idx & 255;
        ((uint32_t*)whhS)[((i2 >> 2) * 256 + col) * 4 + (i2 & 3)] = v;
    }
    // stage-1 weights -> registers (128 u32 = 256 f16)
    uint32_t w1[128];
    {
        const uint4* wp = (const uint4*)w1pk;  // [32][512] uint4
#pragma unroll
        for (int r4 = 0; r4 < 32; ++r4) {
            uint4 v = wp[r4 * 512 + tid];
            w1[4 * r4 + 0] = v.x; w1[4 * r4 + 1] = v.y;
            w1[4 * r4 + 2] = v.z; w1[4 * r4 + 3] = v.w;
        }
    }

    const float br = bias[p], bh = bias[256 + p], bz = bias[512 + p];
    float h = hcar[bb * 256 + p];
    __syncthreads();  // whhS ready; also orders redbuf use below
    float v4[4] = {br * br, bh * bh, bz * bz, h * h};
    bredDB<4>(v4, redbuf[0], tid);
    const float bn2r = 0.5f * v4[0], bn2h = 0.5f * v4[1], bn2z = 0.5f * v4[2];
    float S_h2 = 0.5f * v4[3];

    float* myout = outbase + (size_t)bb * stride_b;
    const float* uxpb = Ux + (size_t)bb * Tc * 768;
    const float* unpb = uxn + (size_t)bb * Tc * 3;

    // prefetch step 0
    float puxr = uxpb[p], puxh = uxpb[256 + p], puxz = uxpb[512 + p];
    float punr = unpb[0], punh = unpb[1], punz = unpb[2];

    for (int t = 0; t < Tc; ++t) {
        const float uxr = puxr, uxh = puxh, uxz = puxz;
        const float unr = punr, unh = punh, unz = punz;

        // ---- expmap0(h): all scalars from carried S_h2 ----
        float hn = sqrtf(S_h2);
        float nrm = fmaxf(hn, MINN);
        float tk0 = tan_k_(nrm, sk);
        float chy = tk0 / nrm;
        float hy = chy * h;
        float Shy2 = chy * chy * S_h2;
        float xnh = fmaxf(tk0 * (hn / nrm), MINN);
        float axh = artan_k_(xnh, sk) / xnh;
        if (ph == 0) ((half_t*)hy2S)[p] = (half_t)hy;
        __syncthreads();  // B1: hy ready

        // prefetch next step's Ux/uxn (hidden under matvec + reductions)
        if (t + 1 < Tc) {
            const float* uxp2 = uxpb + (size_t)(t + 1) * 768;
            puxr = uxp2[p]; puxh = uxp2[256 + p]; puxz = uxp2[512 + p];
            const float* unp2 = unpb + (size_t)(t + 1) * 3;
            punr = unp2[0]; punh = unp2[1]; punz = unp2[2];
        }

        // ---- stage-1 matvec (r,z), pair-split, shfl combine ----
        float pr = 0.f, pz = 0.f;
        {
            const uint4* hp = (const uint4*)hy2S + ph * 16;
#pragma unroll
            for (int c4 = 0; c4 < 4; ++c4) {
                uint32_t hv[16];
#pragma unroll
                for (int u = 0; u < 4; ++u) {
                    uint4 v = hp[c4 * 4 + u];
                    hv[4 * u + 0] = v.x; hv[4 * u + 1] = v.y;
                    hv[4 * u + 2] = v.z; hv[4 * u + 3] = v.w;
                }
#pragma unroll
                for (int m = 0; m < 16; ++m) {
                    pr = dot2acc(w1[c4 * 16 + m], hv[m], pr);
                    pz = dot2acc(w1[64 + c4 * 16 + m], hv[m], pz);
                }
            }
        }
        const float mr = pr + __shfl_xor(pr, 1, 64);
        const float mz = pz + __shfl_xor(pz, 1, 64);

        float vr[11] = {mr * mr, mz * mz, mr * uxr, mz * uxz, mr * br, mz * bz,
                        uxr * br, uxh * bh, uxz * bz, h * uxh, h * bh};
        bredDB<11>(vr, redbuf[0], tid);
        const float S_mr2 = 0.5f * vr[0], S_mz2 = 0.5f * vr[1];
        const float S_mru = 0.5f * vr[2], S_mzu = 0.5f * vr[3];
        const float S_mrb = 0.5f * vr[4], S_mzb = 0.5f * vr[5];
        const float S_ubr = 0.5f * vr[6], S_ubh = 0.5f * vr[7];
        const float S_ubz = 0.5f * vr[8];
        const float S_huxh = 0.5f * vr[9], S_hbh = 0.5f * vr[10];

        float r_t, z_t;
        {   // --- r gate ---
            float mxn = fmaxf(sqrtf(S_mr2), MINN);
            float tk = tan_k_(mxn * axh, sk);
            float f = tk / mxn;
            float x2 = f * f * S_mr2, y2 = unr * unr, xy = f * S_mru;
            float a = 1.f - 2.f * k * xy - k * y2;
            float bq = 1.f + k * x2;
            float d = fmaxf(1.f - 2.f * k * xy + k * k * x2 * y2, MINN);
            float c1 = (a * f * mr + bq * uxr) / d;
            float Sc12 = (a * a * x2 + 2.f * a * bq * xy + bq * bq * y2) / (d * d);
            float Sc1b = (a * f * S_mrb + bq * S_ubr) / d;
            float g = 1.f - 2.f * k * Sc1b - k * bn2r;
            float dl = 1.f + k * Sc12;
            float e = fmaxf(1.f - 2.f * k * Sc1b + k * k * Sc12 * bn2r, MINN);
            float c2 = (g * c1 + dl * br) / e;
            float Sc22 = (g * g * Sc12 + 2.f * g * dl * Sc1b + dl * dl * bn2r) / (e * e);
            float yn = fmaxf(sqrtf(Sc22), MINN);
            float lr = artan_k_(yn, sk) / yn * c2;
            r_t = 1.f / (1.f + expf(-lr));
        }
        {   // --- z gate ---
            float mxn = fmaxf(sqrtf(S_mz2), MINN);
            float tk = tan_k_(mxn * axh, sk);
            float f = tk / mxn;
            float x2 = f * f * S_mz2, y2 = unz * unz, xy = f * S_mzu;
            float a = 1.f - 2.f * k * xy - k * y2;
            float bq = 1.f + k * x2;
            float d = fmaxf(1.f - 2.f * k * xy + k * k * x2 * y2, MINN);
            float c1 = (a * f * mz + bq * uxz) / d;
            float Sc12 = (a * a * x2 + 2.f * a * bq * xy + bq * bq * y2) / (d * d);
            float Sc1b = (a * f * S_mzb + bq * S_ubz) / d;
            float g = 1.f - 2.f * k * Sc1b - k * bn2z;
            float dl = 1.f + k * Sc12;
            float e = fmaxf(1.f - 2.f * k * Sc1b + k * k * Sc12 * bn2z, MINN);
            float c2 = (g * c1 + dl * bz) / e;
            float Sc22 = (g * g * Sc12 + 2.f * g * dl * Sc1b + dl * dl * bn2z) / (e * e);
            float yn = fmaxf(sqrtf(Sc22), MINN);
            float lz = artan_k_(yn, sk) / yn * c2;
            z_t = 1.f / (1.f + expf(-lz));
        }

        // ---- rh = mobius_pointwise_mul(r_t, hy) ----
        float wx = r_t * hy;
        float v1[1] = {wx * wx};
        bredDB<1>(v1, redbuf[1], tid);
        const float S_wx2 = 0.5f * v1[0];
        float wxt = sqrtf(S_wx2);
        float wxn = fmaxf(wxt, MINN);
        float tkw = tan_k_(wxn * axh, sk);
        float fw = tkw / wxn;
        float rhn = tkw * (wxt / wxn);
        if (ph == 0) ((half_t*)rh2S)[p] = (half_t)(fw * wx);
        __syncthreads();  // B5: rh ready

        // ---- stage-2 matvec (h gate) from LDS weights, pair-split ----
        float p0 = 0.f;
        {
            const uint4* rp = (const uint4*)rh2S + ph * 16;
#pragma unroll
            for (int u = 0; u < 16; ++u) {
                uint4 wv = whhS[(ph * 16 + u) * 256 + p];
                uint4 rv = rp[u];
                p0 = dot2acc(wv.x, rv.x, p0);
                p0 = dot2acc(wv.y, rv.y, p0);
                p0 = dot2acc(wv.z, rv.z, p0);
                p0 = dot2acc(wv.w, rv.w, p0);
            }
        }
        const float mh = p0 + __shfl_xor(p0, 1, 64);

        float v4b[4] = {mh * mh, mh * uxh, mh * bh, hy * mh};
        bredDB<4>(v4b, redbuf[0], tid);
        const float S_mh2 = 0.5f * v4b[0], S_mhu = 0.5f * v4b[1];
        const float S_mhb = 0.5f * v4b[2], S_hymh = 0.5f * v4b[3];

        float wz, Sdelta2, z_gate = z_t;
        {
            float xnrh = fmaxf(rhn, MINN);
            float axrh = artan_k_(xnrh, sk) / xnrh;
            float mxn = fmaxf(sqrtf(S_mh2), MINN);
            float tk = tan_k_(mxn * axrh, sk);
            float f = tk / mxn;
            float x2 = f * f * S_mh2, y2 = unh * unh, xy = f * S_mhu;
            float a = 1.f - 2.f * k * xy - k * y2;
            float bq = 1.f + k * x2;
            float d = fmaxf(1.f - 2.f * k * xy + k * k * x2 * y2, MINN);
            float c1 = (a * f * mh + bq * uxh) / d;
            float Sc12 = (a * a * x2 + 2.f * a * bq * xy + bq * bq * y2) / (d * d);
            float Sc1b = (a * f * S_mhb + bq * S_ubh) / d;
            float S_hyc1 = (a * f * S_hymh + bq * chy * S_huxh) / d;
            float g = 1.f - 2.f * k * Sc1b - k * bn2h;
            float dl = 1.f + k * Sc12;
            float e = fmaxf(1.f - 2.f * k * Sc1b + k * k * Sc12 * bn2h, MINN);
            float htl = (g * c1 + dl * bh) / e;
            float Shtl2 = (g * g * Sc12 + 2.f * g * dl * Sc1b + dl * dl * bn2h) / (e * e);
            float S_hyhtl = (g * S_hyc1 + dl * chy * S_hbh) / e;
            // delta = mobius_add(-hy, htl): xy_d = -S_hyhtl
            float ad = 1.f + 2.f * k * S_hyhtl - k * Shtl2;
            float bd = 1.f + k * Shy2;
            float dd = fmaxf(1.f + 2.f * k * S_hyhtl + k * k * Shy2 * Shtl2, MINN);
            float delta = (ad * (-hy) + bd * htl) / dd;
            Sdelta2 = (ad * ad * Shy2 - 2.f * ad * bd * S_hyhtl + bd * bd * Shtl2) / (dd * dd);
            wz = z_gate * delta;
        }
        float v2[2] = {wz * wz, hy * wz};
        bredDB<2>(v2, redbuf[1], tid);
        const float S_wz2 = 0.5f * v2[0], S_hywz = 0.5f * v2[1];

        {
            float dnc = fmaxf(sqrtf(Sdelta2), MINN);
            float axd = artan_k_(dnc, sk) / dnc;
            float wzt = sqrtf(S_wz2);
            float wznc = fmaxf(wzt, MINN);
            float tkzd = tan_k_(wznc * axd, sk);
            float fz = tkzd / wznc;
            float zd = fz * wz;
            float zdn2 = fz * fz * S_wz2;
            float S_hyzd = fz * S_hywz;
            float an = 1.f - 2.f * k * S_hyzd - k * zdn2;
            float bn_ = 1.f + k * Shy2;
            float dnn = fmaxf(1.f - 2.f * k * S_hyzd + k * k * Shy2 * zdn2, MINN);
            float hnew = (an * hy + bn_ * zd) / dnn;
            float Shnew2 = (an * an * Shy2 + 2.f * an * bn_ * S_hyzd + bn_ * bn_ * zdn2) / (dnn * dnn);
            float yn = fmaxf(sqrtf(Shnew2), MINN);
            float ayn = artan_k_(yn, sk) / yn;
            float outv = ayn * hnew;
            if (ph == 0) myout[(size_t)t * stride_t + p] = outv;
            h = outv;
            S_h2 = ayn * ayn * Shnew2;  // carried, no reduction needed
        }
    }
    if (ph == 0) hcar[bb * 256 + p] = h;
}

// ---------- host launcher ----------
extern "C" void kernel_launch(void* const* d_in, const int* in_sizes, int n_in,
                              void* d_out, int out_size, void* d_ws, size_t ws_size,
                              hipStream_t stream) {
    const float* x    = (const float*)d_in[0];
    const float* kptr = (const float*)d_in[1];
    const float* h0   = (const float*)d_in[2];
    const float* wih0 = (const float*)d_in[3];
    const float* whh0 = (const float*)d_in[4];
    const float* b0   = (const float*)d_in[5];
    const float* wih1 = (const float*)d_in[6];
    const float* whh1 = (const float*)d_in[7];
    const float* b1   = (const float*)d_in[8];
    float* out = (float*)d_out;
    float* ws  = (float*)d_ws;

    const int B = 64, T = 1024, H = 256;
    const int CT = 64, NC = 16;
    const int RC = B * CT;  // 4096

    float* wt_ih0 = ws;
    float* wt_ih1 = wt_ih0 + 196608;
    uint32_t* w1pk0  = (uint32_t*)(wt_ih1 + 196608);
    uint32_t* w1pk1  = w1pk0 + 65536;
    uint32_t* whh2g0 = w1pk1 + 65536;
    uint32_t* whh2g1 = whh2g0 + 32768;
    float* hcar  = (float*)(whh2g1 + 32768);
    float* s0    = hcar + 32768;
    float* ax0   = s0 + RC;
    float* s1    = ax0 + RC;
    float* ax1   = s1 + RC;
    float* uxn0  = ax1 + RC;
    float* uxn1  = uxn0 + 3 * RC;
    float* out0c = uxn1 + 3 * RC;
    float* mx0   = out0c + (size_t)RC * H;
    float* mx1   = mx0 + (size_t)RC * 768;

    float* hcar0 = hcar;
    float* hcar1 = hcar + (size_t)B * H;

    dim3 blk(256);
    kt_transpose<<<dim3(1536), blk, 0, stream>>>(wih0, wih1, wt_ih0, wt_ih1);
    kt_prep1<<<dim3(512), blk, 0, stream>>>(whh0, whh1, w1pk0, w1pk1);
    kt_prep2<<<dim3(256), blk, 0, stream>>>(whh0, whh1, whh2g0, whh2g1);
    kt_init<<<dim3(128), blk, 0, stream>>>(h0, hcar);

    const long long sbx = (long long)T * 256;
    const long long sbc = (long long)CT * 256;

    // ---- prologue: layer 0, chunk 0 ----
    {
        const float* xc = x;
        kt_rowscale<<<dim3(RC / 4), blk, 0, stream>>>(xc, sbx, s0, ax0, kptr, 0);
        kt_gemm<<<dim3(12, RC / 64), blk, 0, stream>>>(xc, sbx, s0, wt_ih0, mx0);
        kt_mscale<<<dim3(RC * 3 / 4), blk, 0, stream>>>(mx0, ax0, uxn0, kptr);
        kt_scan2<<<dim3(B), dim3(512), 0, stream>>>(
            mx0, uxn0, w1pk0, whh2g0, b0, hcar0, out0c, sbc, 256LL,
            mx0, uxn0, w1pk0, whh2g0, b0, hcar0, out0c, sbc, 256LL,
            kptr, CT, B);
    }
    // ---- steady state: dual scans (L0 chunk c || L1 chunk c-1) ----
    for (int c = 1; c < NC; ++c) {
        const float* xc = x + (size_t)c * CT * 256;
        kt_rowscale<<<dim3(RC / 4), blk, 0, stream>>>(xc, sbx, s0, ax0, kptr, 0);
        kt_gemm<<<dim3(12, RC / 64), blk, 0, stream>>>(xc, sbx, s0, wt_ih0, mx0);
        kt_mscale<<<dim3(RC * 3 / 4), blk, 0, stream>>>(mx0, ax0, uxn0, kptr);
        kt_rowscale<<<dim3(RC / 4), blk, 0, stream>>>(out0c, sbc, s1, ax1, kptr, 1);
        kt_gemm<<<dim3(12, RC / 64), blk, 0, stream>>>(out0c, sbc, s1, wt_ih1, mx1);
        kt_mscale<<<dim3(RC * 3 / 4), blk, 0, stream>>>(mx1, ax1, uxn1, kptr);
        kt_scan2<<<dim3(2 * B), dim3(512), 0, stream>>>(
            mx0, uxn0, w1pk0, whh2g0, b0, hcar0, out0c, sbc, 256LL,
            mx1, uxn1, w1pk1, whh2g1, b1, hcar1,
            out + (size_t)(c - 1) * CT * B * H, 256LL, (long long)B * H,
            kptr, CT, B);
    }
    // ---- epilogue: layer 1, chunk NC-1 ----
    {
        kt_rowscale<<<dim3(RC / 4), blk, 0, stream>>>(out0c, sbc, s1, ax1, kptr, 1);
        kt_gemm<<<dim3(12, RC / 64), blk, 0, stream>>>(out0c, sbc, s1, wt_ih1, mx1);
        kt_mscale<<<dim3(RC * 3 / 4), blk, 0, stream>>>(mx1, ax1, uxn1, kptr);
        kt_scan2<<<dim3(B), dim3(512), 0, stream>>>(
            mx1, uxn1, w1pk1, whh2g1, b1, hcar1,
            out + (size_t)(NC - 1) * CT * B * H, 256LL, (long long)B * H,
            mx1, uxn1, w1pk1, whh2g1, b1, hcar1,
            out + (size_t)(NC - 1) * CT * B * H, 256LL, (long long)B * H,
            kptr, CT, B);
    }
    kt_final<<<dim3(128), blk, 0, stream>>>(hcar, out + (size_t)T * B * H);
}

// Round 6
// 7910.337 us; speedup vs baseline: 1.7594x; 1.7594x over previous
//
#include <hip/hip_runtime.h>
#include <cstdint>
#include <cstddef>

#define MINN 1e-15f
#define EPSA 1e-7f
#define C_L2E 1.44269504088896341f
#define C_LN2 0.69314718055994531f

typedef _Float16 half_t;
typedef _Float16 half2_t __attribute__((ext_vector_type(2)));

// ---------- fast-math helpers (native, ~1 ulp) ----------
__device__ __forceinline__ float fexp2_(float x) {
#if defined(__has_builtin) && __has_builtin(__builtin_amdgcn_exp2f)
    return __builtin_amdgcn_exp2f(x);
#else
    return exp2f(x);
#endif
}
__device__ __forceinline__ float flog2_(float x) {
#if defined(__has_builtin) && __has_builtin(__builtin_amdgcn_logf)
    return __builtin_amdgcn_logf(x);
#else
    return log2f(x);
#endif
}
__device__ __forceinline__ float frcp_(float x) {
#if defined(__has_builtin) && __has_builtin(__builtin_amdgcn_rcpf)
    return __builtin_amdgcn_rcpf(x);
#else
    return 1.f / x;
#endif
}
// tan_k: tanh(clamp(sk*u))/sk via exp2
__device__ __forceinline__ float tan_k_(float u, float sk, float rsk) {
    float a = fminf(fmaxf(sk * u, -15.f), 15.f);
    float t = fexp2_(a * (2.f * C_L2E));
    return (1.f - 2.f * frcp_(t + 1.f)) * rsk;
}
// artan_k: atanh(clamp(sk*u))/sk via log2
__device__ __forceinline__ float artan_k_(float u, float sk, float rsk) {
    float a = fminf(fmaxf(sk * u, -1.f + EPSA), 1.f - EPSA);
    return flog2_((1.f + a) * frcp_(1.f - a)) * (0.5f * C_LN2) * rsk;
}
__device__ __forceinline__ float sigm_(float x) {
    return frcp_(1.f + fexp2_(-x * C_L2E));
}
__device__ __forceinline__ float wave_sum(float v) {
#pragma unroll
    for (int off = 32; off; off >>= 1) v += __shfl_xor(v, off, 64);
    return v;
}
// f16 pair dot-accumulate: acc += a.h0*b.h0 + a.h1*b.h1 (f32 accum)
__device__ __forceinline__ float dot2acc(uint32_t w, uint32_t h, float acc) {
#if defined(__has_builtin) && __has_builtin(__builtin_amdgcn_fdot2)
    return __builtin_amdgcn_fdot2(__builtin_bit_cast(half2_t, w),
                                  __builtin_bit_cast(half2_t, h), acc, false);
#else
    half2_t a = __builtin_bit_cast(half2_t, w);
    half2_t b = __builtin_bit_cast(half2_t, h);
    acc = fmaf((float)a[0], (float)b[0], acc);
    return fmaf((float)a[1], (float)b[1], acc);
#endif
}
// block(512)-wide reduce of N values, broadcast. ONE internal barrier;
// caller guarantees buffer alternation between consecutive uses.
template <int N>
__device__ __forceinline__ void bredDB(float* v, float* redbuf, int tid) {
#pragma unroll
    for (int n = 0; n < N; ++n) {
#pragma unroll
        for (int off = 32; off; off >>= 1) v[n] += __shfl_xor(v[n], off, 64);
    }
    int wave = tid >> 6, lane = tid & 63;
#pragma unroll
    for (int n = 0; n < N; ++n)
        if (lane == n) redbuf[n * 8 + wave] = v[n];
    __syncthreads();
#pragma unroll
    for (int n = 0; n < N; ++n) {
        float4 a = *(float4*)&redbuf[n * 8];
        float4 b = *(float4*)&redbuf[n * 8 + 4];
        v[n] = ((a.x + a.y) + (a.z + a.w)) + ((b.x + b.y) + (b.z + b.w));
    }
}

// ---------- K1: transpose 2 ih weight matrices [768x256] -> [256x768] ----------
__global__ __launch_bounds__(256) void kt_transpose(
    const float* __restrict__ a0, const float* __restrict__ a1,
    float* __restrict__ o0, float* __restrict__ o1) {
    int idx = blockIdx.x * 256 + threadIdx.x;
    int m = idx / 196608, rem = idx % 196608;
    int j = rem >> 8, kk = rem & 255;
    const float* in = (m == 0) ? a0 : a1;
    float* outp     = (m == 0) ? o0 : o1;
    outp[kk * 768 + j] = in[j * 256 + kk];
}

// ---------- prep1: pack stage-1 (W_hr,W_hz) f16 per-thread fragments ----------
// HALF-WAVE pair layout: thread t: lane=t&63, wave=t>>6,
//   p = wave*32 + (lane&31)  (output index), ph = lane>>5 (i-half).
// Register m in [0,128): g=m>>6 (0=r,1=z), mi=m&63, i=ph*128+2*mi.
// Stored for uint4-coalesced loads: u32 index e = (m>>2)*2048 + t*4 + (m&3).
__global__ __launch_bounds__(256) void kt_prep1(
    const float* __restrict__ whh0, const float* __restrict__ whh1,
    uint32_t* __restrict__ p0, uint32_t* __restrict__ p1) {
    int idx = blockIdx.x * 256 + threadIdx.x;  // 131072
    int l = idx >> 16, e = idx & 65535;
    int r4 = e >> 11, rem = e & 2047;
    int t = rem >> 2, m = r4 * 4 + (rem & 3);
    int lane = t & 63, wave = t >> 6;
    int p = wave * 32 + (lane & 31), ph = lane >> 5;
    int g = m >> 6, mi = m & 63;
    int row = g ? (512 + p) : p;
    int i = ph * 128 + 2 * mi;
    const float* w = l ? whh1 : whh0;
    half2_t hv;
    hv[0] = (half_t)w[row * 256 + i];
    hv[1] = (half_t)w[row * 256 + i + 1];
    (l ? p1 : p0)[e] = __builtin_bit_cast(uint32_t, hv);
}

// ---------- prep2: pack stage-2 (W_hh_) f16 [i2][j] half2 ----------
__global__ __launch_bounds__(256) void kt_prep2(
    const float* __restrict__ whh0, const float* __restrict__ whh1,
    uint32_t* __restrict__ p0, uint32_t* __restrict__ p1) {
    int idx = blockIdx.x * 256 + threadIdx.x;  // 65536
    int l = idx >> 15, e = idx & 32767;
    int i2 = e >> 8, j = e & 255;
    const float* w = l ? whh1 : whh0;
    half2_t hv;
    hv[0] = (half_t)w[(256 + j) * 256 + 2 * i2];
    hv[1] = (half_t)w[(256 + j) * 256 + 2 * i2 + 1];
    (l ? p1 : p0)[e] = __builtin_bit_cast(uint32_t, hv);
}

// ---------- init / final ----------
__global__ __launch_bounds__(256) void kt_init(
    const float* __restrict__ h0, float* __restrict__ hcar) {
    int i = blockIdx.x * 256 + threadIdx.x;
    hcar[i] = h0[i];
}
__global__ __launch_bounds__(256) void kt_final(
    const float* __restrict__ hcar, float* __restrict__ dst) {
    int i = blockIdx.x * 256 + threadIdx.x;
    dst[i] = hcar[i];
}

// ---------- rowscale / gemm / mscale ----------
__global__ __launch_bounds__(256) void kt_rowscale(
    const float* __restrict__ src, long long strideB,
    float* __restrict__ s_arr, float* __restrict__ ax_arr,
    const float* __restrict__ kptr, int mode) {
    int lane = threadIdx.x & 63;
    int r = blockIdx.x * 4 + (threadIdx.x >> 6);
    float k = kptr[0], sk = sqrtf(-k), rsk = frcp_(sk);
    size_t off = (size_t)(r >> 6) * strideB + (size_t)(r & 63) * 256 + lane * 4;
    float4 v = *(const float4*)&src[off];
    float n2 = wave_sum(v.x * v.x + v.y * v.y + v.z * v.z + v.w * v.w);
    float n = sqrtf(n2);
    float s, xn;
    if (mode == 0) {
        float nrm = fmaxf(n, MINN);
        float tk = tan_k_(nrm, sk, rsk);
        s = tk * frcp_(nrm);
        xn = fmaxf(tk * (n * frcp_(nrm)), MINN);
    } else {
        s = 1.f;
        xn = fmaxf(n, MINN);
    }
    float ax = artan_k_(xn, sk, rsk) * frcp_(xn);
    if (lane == 0) { s_arr[r] = s; ax_arr[r] = ax; }
}

__global__ __launch_bounds__(256) void kt_gemm(
    const float* __restrict__ A, long long strideB,
    const float* __restrict__ s_arr,
    const float* __restrict__ Bt, float* __restrict__ C) {
    __shared__ float As[16][68];
    __shared__ float Bs[16][68];
    __shared__ float sS[64];
    int tid = threadIdx.x;
    int row0 = blockIdx.y * 64, col0 = blockIdx.x * 64;
    if (tid < 64) sS[tid] = s_arr[row0 + tid];
    int ty = tid >> 4, tx = tid & 15;
    int ra = tid >> 2, kq = tid & 3;
    int kb = tid >> 4, cq = tid & 15;
    float acc[4][4] = {};
    __syncthreads();
#pragma unroll 1
    for (int kt = 0; kt < 16; ++kt) {
        int k0 = kt * 16;
        int rc = row0 + ra;
        size_t aoff = (size_t)(rc >> 6) * strideB + (size_t)(rc & 63) * 256 + k0 + kq * 4;
        float4 av = *(const float4*)&A[aoff];
        float sc = sS[ra];
        float4 bv = *(const float4*)&Bt[(size_t)(k0 + kb) * 768 + col0 + cq * 4];
        As[kq * 4 + 0][ra] = av.x * sc;
        As[kq * 4 + 1][ra] = av.y * sc;
        As[kq * 4 + 2][ra] = av.z * sc;
        As[kq * 4 + 3][ra] = av.w * sc;
        *(float4*)&Bs[kb][cq * 4] = bv;
        __syncthreads();
#pragma unroll
        for (int kk = 0; kk < 16; ++kk) {
            float4 a4 = *(const float4*)&As[kk][ty * 4];
            float4 b4 = *(const float4*)&Bs[kk][tx * 4];
            float aa[4] = {a4.x, a4.y, a4.z, a4.w};
            float bb[4] = {b4.x, b4.y, b4.z, b4.w};
#pragma unroll
            for (int i = 0; i < 4; ++i)
#pragma unroll
                for (int j = 0; j < 4; ++j)
                    acc[i][j] = fmaf(aa[i], bb[j], acc[i][j]);
        }
        __syncthreads();
    }
#pragma unroll
    for (int i = 0; i < 4; ++i) {
        size_t row = (size_t)row0 + ty * 4 + i;
        *(float4*)&C[row * 768 + col0 + tx * 4] =
            make_float4(acc[i][0], acc[i][1], acc[i][2], acc[i][3]);
    }
}

// scales mx in place, stores ||Ux|| and (Ux . bias) per (row,gate)
__global__ __launch_bounds__(256) void kt_mscale(
    float* __restrict__ mx, const float* __restrict__ ax_arr,
    float* __restrict__ uxn, float* __restrict__ uxb,
    const float* __restrict__ bias, const float* __restrict__ kptr) {
    int lane = threadIdx.x & 63;
    int p = blockIdx.x * 4 + (threadIdx.x >> 6);
    int r = p / 3;
    int g = p - r * 3;
    float k = kptr[0], sk = sqrtf(-k), rsk = frcp_(sk);
    float* ptr = mx + (size_t)r * 768 + g * 256 + lane * 4;
    float4 v = *(const float4*)ptr;
    float4 b4 = *(const float4*)&bias[g * 256 + lane * 4];
    float n2 = wave_sum(v.x * v.x + v.y * v.y + v.z * v.z + v.w * v.w);
    float vb = wave_sum(v.x * b4.x + v.y * b4.y + v.z * b4.z + v.w * b4.w);
    float nt = sqrtf(n2);
    float mxn = fmaxf(nt, MINN);
    float arg = mxn * ax_arr[r];
    float tk = tan_k_(arg, sk, rsk);
    float f = tk * frcp_(mxn);
    v.x *= f; v.y *= f; v.z *= f; v.w *= f;
    *(float4*)ptr = v;
    if (lane == 0) { uxn[p] = tk * (nt * frcp_(mxn)); uxb[p] = f * vb; }
}

// ---------- K6: persistent-weight scan, dual-role, half-wave pair layout ----------
// Thread: lane=tid&63, wave=tid>>6; p = wave*32+(lane&31), ph = lane>>5.
// Pair partners are lanes (l, l^32) in the same wave -> shfl_xor(32).
// Block sums duplicated per pair -> scale 0.5 after reduce.
__global__ __launch_bounds__(512, 1) void kt_scan2(
    const float* __restrict__ Ux_0, const float* __restrict__ uxn_0,
    const float* __restrict__ uxb_0,
    const uint32_t* __restrict__ w1pk_0, const uint32_t* __restrict__ whh2g_0,
    const float* __restrict__ bias_0, float* __restrict__ hcar_0,
    float* __restrict__ out_0, long long sb_0, long long st_0,
    const float* __restrict__ Ux_1, const float* __restrict__ uxn_1,
    const float* __restrict__ uxb_1,
    const uint32_t* __restrict__ w1pk_1, const uint32_t* __restrict__ whh2g_1,
    const float* __restrict__ bias_1, float* __restrict__ hcar_1,
    float* __restrict__ out_1, long long sb_1, long long st_1,
    const float* __restrict__ kptr, int Tc, int nrole0) {
    __shared__ uint4 whhS[8192];       // 128 KiB: W_hh_ f16, [i2-quad][j]
    __shared__ uint32_t hy2S[128];     // hy as 128 half2
    __shared__ uint32_t rh2S[128];     // wx (unscaled rh) as 128 half2
    __shared__ float redbuf[2][96];    // double-buffered reduce scratch

    const int tid = threadIdx.x;
    const int role = (blockIdx.x >= nrole0) ? 1 : 0;
    const int bb = role ? (int)blockIdx.x - nrole0 : (int)blockIdx.x;

    const float* Ux      = role ? Ux_1 : Ux_0;
    const float* uxn     = role ? uxn_1 : uxn_0;
    const float* uxb     = role ? uxb_1 : uxb_0;
    const uint32_t* w1pk = role ? w1pk_1 : w1pk_0;
    const uint32_t* whh2g= role ? whh2g_1 : whh2g_0;
    const float* bias    = role ? bias_1 : bias_0;
    float* hcar          = role ? hcar_1 : hcar_0;
    float* outbase       = role ? out_1 : out_0;
    const long long stride_b = role ? sb_1 : sb_0;
    const long long stride_t = role ? st_1 : st_0;

    const int lane = tid & 63, wave = tid >> 6;
    const int p = wave * 32 + (lane & 31), ph = lane >> 5;
    const float k = kptr[0], sk = sqrtf(-k), rsk = frcp_(sk);

    // stage-2 weights -> LDS
    for (int idx = tid; idx < 32768; idx += 512) {
        uint32_t v = whh2g[idx];
        int i2 = idx >> 8, col = idx & 255;
        ((uint32_t*)whhS)[((i2 >> 2) * 256 + col) * 4 + (i2 & 3)] = v;
    }
    // stage-1 weights -> registers (128 u32 = 256 f16)
    uint32_t w1[128];
    {
        const uint4* wp = (const uint4*)w1pk;  // [32][512] uint4
#pragma unroll
        for (int r4 = 0; r4 < 32; ++r4) {
            uint4 v = wp[r4 * 512 + tid];
            w1[4 * r4 + 0] = v.x; w1[4 * r4 + 1] = v.y;
            w1[4 * r4 + 2] = v.z; w1[4 * r4 + 3] = v.w;
        }
    }

    const float br = bias[p], bh = bias[256 + p], bz = bias[512 + p];
    float h = hcar[bb * 256 + p];
    __syncthreads();  // whhS ready
    float v4[4] = {br * br, bh * bh, bz * bz, h * h};
    bredDB<4>(v4, redbuf[0], tid);
    const float bn2r = 0.5f * v4[0], bn2h = 0.5f * v4[1], bn2z = 0.5f * v4[2];
    float S_h2 = 0.5f * v4[3];

    float* myout = outbase + (size_t)bb * stride_b;
    const float* uxpb = Ux + (size_t)bb * Tc * 768;
    const float* unpb = uxn + (size_t)bb * Tc * 3;
    const float* ubpb = uxb + (size_t)bb * Tc * 3;

    // prefetch step 0
    float puxr = uxpb[p], puxh = uxpb[256 + p], puxz = uxpb[512 + p];
    float punr = unpb[0], punh = unpb[1], punz = unpb[2];
    float pubr = ubpb[0], pubh = ubpb[1], pubz = ubpb[2];

    for (int t = 0; t < Tc; ++t) {
        const float uxr = puxr, uxh = puxh, uxz = puxz;
        const float unr = punr, unh = punh, unz = punz;
        const float S_ubr = pubr, S_ubh = pubh, S_ubz = pubz;

        // ---- expmap0(h): scalars from carried S_h2 ----
        float hn = sqrtf(S_h2);
        float nrm = fmaxf(hn, MINN);
        float tk0 = tan_k_(nrm, sk, rsk);
        float chy = tk0 * frcp_(nrm);
        float hy = chy * h;
        float Shy2 = chy * chy * S_h2;
        float xnh = fmaxf(tk0 * (hn * frcp_(nrm)), MINN);
        float axh = artan_k_(xnh, sk, rsk) * frcp_(xnh);
        if (ph == 0) ((half_t*)hy2S)[p] = (half_t)hy;
        __syncthreads();  // B1: hy ready

        // prefetch next step (hidden under matvec + reductions)
        if (t + 1 < Tc) {
            const float* uxp2 = uxpb + (size_t)(t + 1) * 768;
            puxr = uxp2[p]; puxh = uxp2[256 + p]; puxz = uxp2[512 + p];
            const float* unp2 = unpb + (size_t)(t + 1) * 3;
            punr = unp2[0]; punh = unp2[1]; punz = unp2[2];
            const float* ubp2 = ubpb + (size_t)(t + 1) * 3;
            pubr = ubp2[0]; pubh = ubp2[1]; pubz = ubp2[2];
        }

        // ---- stage-1 matvec (r,z), half-split, 2-deep accumulators ----
        float pr0 = 0.f, pr1 = 0.f, pz0 = 0.f, pz1 = 0.f;
        {
            const uint4* hp = (const uint4*)hy2S + ph * 16;
#pragma unroll
            for (int c4 = 0; c4 < 4; ++c4) {
                uint32_t hv[16];
#pragma unroll
                for (int u = 0; u < 4; ++u) {
                    uint4 v = hp[c4 * 4 + u];
                    hv[4 * u + 0] = v.x; hv[4 * u + 1] = v.y;
                    hv[4 * u + 2] = v.z; hv[4 * u + 3] = v.w;
                }
#pragma unroll
                for (int m = 0; m < 16; ++m) {
                    if (c4 < 2) {
                        pr0 = dot2acc(w1[c4 * 16 + m], hv[m], pr0);
                        pz0 = dot2acc(w1[64 + c4 * 16 + m], hv[m], pz0);
                    } else {
                        pr1 = dot2acc(w1[c4 * 16 + m], hv[m], pr1);
                        pz1 = dot2acc(w1[64 + c4 * 16 + m], hv[m], pz1);
                    }
                }
            }
        }
        float pr = pr0 + pr1, pz = pz0 + pz1;
        const float mr = pr + __shfl_xor(pr, 32, 64);
        const float mz = pz + __shfl_xor(pz, 32, 64);

        float vr[8] = {mr * mr, mz * mz, mr * uxr, mz * uxz,
                       mr * br, mz * bz, h * uxh, h * bh};
        bredDB<8>(vr, redbuf[0], tid);
        const float S_mr2 = 0.5f * vr[0], S_mz2 = 0.5f * vr[1];
        const float S_mru = 0.5f * vr[2], S_mzu = 0.5f * vr[3];
        const float S_mrb = 0.5f * vr[4], S_mzb = 0.5f * vr[5];
        const float S_huxh = 0.5f * vr[6], S_hbh = 0.5f * vr[7];

        float r_t, z_t;
        {   // --- r gate ---
            float mxn = fmaxf(sqrtf(S_mr2), MINN);
            float tk = tan_k_(mxn * axh, sk, rsk);
            float f = tk * frcp_(mxn);
            float x2 = f * f * S_mr2, y2 = unr * unr, xy = f * S_mru;
            float a = 1.f - 2.f * k * xy - k * y2;
            float bq = 1.f + k * x2;
            float rd = frcp_(fmaxf(1.f - 2.f * k * xy + k * k * x2 * y2, MINN));
            float c1 = (a * f * mr + bq * uxr) * rd;
            float Sc12 = (a * a * x2 + 2.f * a * bq * xy + bq * bq * y2) * (rd * rd);
            float Sc1b = (a * f * S_mrb + bq * S_ubr) * rd;
            float g = 1.f - 2.f * k * Sc1b - k * bn2r;
            float dl = 1.f + k * Sc12;
            float re = frcp_(fmaxf(1.f - 2.f * k * Sc1b + k * k * Sc12 * bn2r, MINN));
            float c2 = (g * c1 + dl * br) * re;
            float Sc22 = (g * g * Sc12 + 2.f * g * dl * Sc1b + dl * dl * bn2r) * (re * re);
            float yn = fmaxf(sqrtf(Sc22), MINN);
            float lr = artan_k_(yn, sk, rsk) * frcp_(yn) * c2;
            r_t = sigm_(lr);
        }
        {   // --- z gate ---
            float mxn = fmaxf(sqrtf(S_mz2), MINN);
            float tk = tan_k_(mxn * axh, sk, rsk);
            float f = tk * frcp_(mxn);
            float x2 = f * f * S_mz2, y2 = unz * unz, xy = f * S_mzu;
            float a = 1.f - 2.f * k * xy - k * y2;
            float bq = 1.f + k * x2;
            float rd = frcp_(fmaxf(1.f - 2.f * k * xy + k * k * x2 * y2, MINN));
            float c1 = (a * f * mz + bq * uxz) * rd;
            float Sc12 = (a * a * x2 + 2.f * a * bq * xy + bq * bq * y2) * (rd * rd);
            float Sc1b = (a * f * S_mzb + bq * S_ubz) * rd;
            float g = 1.f - 2.f * k * Sc1b - k * bn2z;
            float dl = 1.f + k * Sc12;
            float re = frcp_(fmaxf(1.f - 2.f * k * Sc1b + k * k * Sc12 * bn2z, MINN));
            float c2 = (g * c1 + dl * bz) * re;
            float Sc22 = (g * g * Sc12 + 2.f * g * dl * Sc1b + dl * dl * bn2z) * (re * re);
            float yn = fmaxf(sqrtf(Sc22), MINN);
            float lz = artan_k_(yn, sk, rsk) * frcp_(yn) * c2;
            z_t = sigm_(lz);
        }

        // ---- rh: publish UNSCALED wx; merge S_wx2 reduction into same barrier ----
        float wx = r_t * hy;
        if (ph == 0) ((half_t*)rh2S)[p] = (half_t)wx;
        float v1 = wave_sum(wx * wx);
        if (lane == 0) redbuf[1][wave] = v1;
        __syncthreads();  // B_B: rh/wx ready + v1 partials ready

        float S_wx2;
        {
            float4 a = *(float4*)&redbuf[1][0];
            float4 b = *(float4*)&redbuf[1][4];
            S_wx2 = 0.5f * (((a.x + a.y) + (a.z + a.w)) + ((b.x + b.y) + (b.z + b.w)));
        }
        float wxt = sqrtf(S_wx2);
        float wxn = fmaxf(wxt, MINN);
        float tkw = tan_k_(wxn * axh, sk, rsk);
        float fw = tkw * frcp_(wxn);      // rh = fw * wx (fw is block scalar)
        float rhn = tkw * (wxt * frcp_(wxn));

        // ---- stage-2 matvec (h gate), half-split, 2-deep accumulators ----
        float q0 = 0.f, q1 = 0.f;
        {
            const uint4* rp = (const uint4*)rh2S + ph * 16;
#pragma unroll
            for (int u = 0; u < 16; ++u) {
                uint4 wv = whhS[(ph * 16 + u) * 256 + p];
                uint4 rv = rp[u];
                if (u < 8) {
                    q0 = dot2acc(wv.x, rv.x, q0);
                    q0 = dot2acc(wv.y, rv.y, q0);
                    q0 = dot2acc(wv.z, rv.z, q0);
                    q0 = dot2acc(wv.w, rv.w, q0);
                } else {
                    q1 = dot2acc(wv.x, rv.x, q1);
                    q1 = dot2acc(wv.y, rv.y, q1);
                    q1 = dot2acc(wv.z, rv.z, q1);
                    q1 = dot2acc(wv.w, rv.w, q1);
                }
            }
        }
        float qq = q0 + q1;
        const float mh = fw * (qq + __shfl_xor(qq, 32, 64));

        float v4b[4] = {mh * mh, mh * uxh, mh * bh, hy * mh};
        bredDB<4>(v4b, redbuf[0], tid);
        const float S_mh2 = 0.5f * v4b[0], S_mhu = 0.5f * v4b[1];
        const float S_mhb = 0.5f * v4b[2], S_hymh = 0.5f * v4b[3];

        float wz, Sdelta2;
        {
            float xnrh = fmaxf(rhn, MINN);
            float axrh = artan_k_(xnrh, sk, rsk) * frcp_(xnrh);
            float mxn = fmaxf(sqrtf(S_mh2), MINN);
            float tk = tan_k_(mxn * axrh, sk, rsk);
            float f = tk * frcp_(mxn);
            float x2 = f * f * S_mh2, y2 = unh * unh, xy = f * S_mhu;
            float a = 1.f - 2.f * k * xy - k * y2;
            float bq = 1.f + k * x2;
            float rd = frcp_(fmaxf(1.f - 2.f * k * xy + k * k * x2 * y2, MINN));
            float c1 = (a * f * mh + bq * uxh) * rd;
            float Sc12 = (a * a * x2 + 2.f * a * bq * xy + bq * bq * y2) * (rd * rd);
            float Sc1b = (a * f * S_mhb + bq * S_ubh) * rd;
            float S_hyc1 = (a * f * S_hymh + bq * chy * S_huxh) * rd;
            float g = 1.f - 2.f * k * Sc1b - k * bn2h;
            float dl = 1.f + k * Sc12;
            float re = frcp_(fmaxf(1.f - 2.f * k * Sc1b + k * k * Sc12 * bn2h, MINN));
            float htl = (g * c1 + dl * bh) * re;
            float Shtl2 = (g * g * Sc12 + 2.f * g * dl * Sc1b + dl * dl * bn2h) * (re * re);
            float S_hyhtl = (g * S_hyc1 + dl * chy * S_hbh) * re;
            // delta = mobius_add(-hy, htl): xy_d = -S_hyhtl
            float ad = 1.f + 2.f * k * S_hyhtl - k * Shtl2;
            float bd = 1.f + k * Shy2;
            float rdd = frcp_(fmaxf(1.f + 2.f * k * S_hyhtl + k * k * Shy2 * Shtl2, MINN));
            float delta = (ad * (-hy) + bd * htl) * rdd;
            Sdelta2 = (ad * ad * Shy2 - 2.f * ad * bd * S_hyhtl + bd * bd * Shtl2) * (rdd * rdd);
            wz = z_t * delta;
        }
        float v2[2] = {wz * wz, hy * wz};
        bredDB<2>(v2, redbuf[1], tid);
        const float S_wz2 = 0.5f * v2[0], S_hywz = 0.5f * v2[1];

        {
            float dnc = fmaxf(sqrtf(Sdelta2), MINN);
            float axd = artan_k_(dnc, sk, rsk) * frcp_(dnc);
            float wzt = sqrtf(S_wz2);
            float wznc = fmaxf(wzt, MINN);
            float tkzd = tan_k_(wznc * axd, sk, rsk);
            float fz = tkzd * frcp_(wznc);
            float zd = fz * wz;
            float zdn2 = fz * fz * S_wz2;
            float S_hyzd = fz * S_hywz;
            float an = 1.f - 2.f * k * S_hyzd - k * zdn2;
            float bn_ = 1.f + k * Shy2;
            float rdn = frcp_(fmaxf(1.f - 2.f * k * S_hyzd + k * k * Shy2 * zdn2, MINN));
            float hnew = (an * hy + bn_ * zd) * rdn;
            float Shnew2 = (an * an * Shy2 + 2.f * an * bn_ * S_hyzd + bn_ * bn_ * zdn2) * (rdn * rdn);
            float yn = fmaxf(sqrtf(Shnew2), MINN);
            float ayn = artan_k_(yn, sk, rsk) * frcp_(yn);
            float outv = ayn * hnew;
            if (ph == 0) myout[(size_t)t * stride_t + p] = outv;
            h = outv;
            S_h2 = ayn * ayn * Shnew2;  // carried, no reduction needed
        }
    }
    if (ph == 0) hcar[bb * 256 + p] = h;
}

// ---------- host launcher ----------
extern "C" void kernel_launch(void* const* d_in, const int* in_sizes, int n_in,
                              void* d_out, int out_size, void* d_ws, size_t ws_size,
                              hipStream_t stream) {
    const float* x    = (const float*)d_in[0];
    const float* kptr = (const float*)d_in[1];
    const float* h0   = (const float*)d_in[2];
    const float* wih0 = (const float*)d_in[3];
    const float* whh0 = (const float*)d_in[4];
    const float* b0   = (const float*)d_in[5];
    const float* wih1 = (const float*)d_in[6];
    const float* whh1 = (const float*)d_in[7];
    const float* b1   = (const float*)d_in[8];
    float* out = (float*)d_out;
    float* ws  = (float*)d_ws;

    const int B = 64, T = 1024, H = 256;
    const int CT = 64, NC = 16;
    const int RC = B * CT;  // 4096

    float* wt_ih0 = ws;
    float* wt_ih1 = wt_ih0 + 196608;
    uint32_t* w1pk0  = (uint32_t*)(wt_ih1 + 196608);
    uint32_t* w1pk1  = w1pk0 + 65536;
    uint32_t* whh2g0 = w1pk1 + 65536;
    uint32_t* whh2g1 = whh2g0 + 32768;
    float* hcar  = (float*)(whh2g1 + 32768);
    float* s0    = hcar + 32768;
    float* ax0   = s0 + RC;
    float* s1    = ax0 + RC;
    float* ax1   = s1 + RC;
    float* uxn0  = ax1 + RC;
    float* uxn1  = uxn0 + 3 * RC;
    float* uxb0  = uxn1 + 3 * RC;
    float* uxb1  = uxb0 + 3 * RC;
    float* out0c = uxb1 + 3 * RC;
    float* mx0   = out0c + (size_t)RC * H;
    float* mx1   = mx0 + (size_t)RC * 768;

    float* hcar0 = hcar;
    float* hcar1 = hcar + (size_t)B * H;

    dim3 blk(256);
    kt_transpose<<<dim3(1536), blk, 0, stream>>>(wih0, wih1, wt_ih0, wt_ih1);
    kt_prep1<<<dim3(512), blk, 0, stream>>>(whh0, whh1, w1pk0, w1pk1);
    kt_prep2<<<dim3(256), blk, 0, stream>>>(whh0, whh1, whh2g0, whh2g1);
    kt_init<<<dim3(128), blk, 0, stream>>>(h0, hcar);

    const long long sbx = (long long)T * 256;
    const long long sbc = (long long)CT * 256;

    // ---- prologue: layer 0, chunk 0 ----
    {
        const float* xc = x;
        kt_rowscale<<<dim3(RC / 4), blk, 0, stream>>>(xc, sbx, s0, ax0, kptr, 0);
        kt_gemm<<<dim3(12, RC / 64), blk, 0, stream>>>(xc, sbx, s0, wt_ih0, mx0);
        kt_mscale<<<dim3(RC * 3 / 4), blk, 0, stream>>>(mx0, ax0, uxn0, uxb0, b0, kptr);
        kt_scan2<<<dim3(B), dim3(512), 0, stream>>>(
            mx0, uxn0, uxb0, w1pk0, whh2g0, b0, hcar0, out0c, sbc, 256LL,
            mx0, uxn0, uxb0, w1pk0, whh2g0, b0, hcar0, out0c, sbc, 256LL,
            kptr, CT, B);
    }
    // ---- steady state: dual scans (L0 chunk c || L1 chunk c-1) ----
    for (int c = 1; c < NC; ++c) {
        const float* xc = x + (size_t)c * CT * 256;
        kt_rowscale<<<dim3(RC / 4), blk, 0, stream>>>(xc, sbx, s0, ax0, kptr, 0);
        kt_gemm<<<dim3(12, RC / 64), blk, 0, stream>>>(xc, sbx, s0, wt_ih0, mx0);
        kt_mscale<<<dim3(RC * 3 / 4), blk, 0, stream>>>(mx0, ax0, uxn0, uxb0, b0, kptr);
        kt_rowscale<<<dim3(RC / 4), blk, 0, stream>>>(out0c, sbc, s1, ax1, kptr, 1);
        kt_gemm<<<dim3(12, RC / 64), blk, 0, stream>>>(out0c, sbc, s1, wt_ih1, mx1);
        kt_mscale<<<dim3(RC * 3 / 4), blk, 0, stream>>>(mx1, ax1, uxn1, uxb1, b1, kptr);
        kt_scan2<<<dim3(2 * B), dim3(512), 0, stream>>>(
            mx0, uxn0, uxb0, w1pk0, whh2g0, b0, hcar0, out0c, sbc, 256LL,
            mx1, uxn1, uxb1, w1pk1, whh2g1, b1, hcar1,
            out + (size_t)(c - 1) * CT * B * H, 256LL, (long long)B * H,
            kptr, CT, B);
    }
    // ---- epilogue: layer 1, chunk NC-1 ----
    {
        kt_rowscale<<<dim3(RC / 4), blk, 0, stream>>>(out0c, sbc, s1, ax1, kptr, 1);
        kt_gemm<<<dim3(12, RC / 64), blk, 0, stream>>>(out0c, sbc, s1, wt_ih1, mx1);
        kt_mscale<<<dim3(RC * 3 / 4), blk, 0, stream>>>(mx1, ax1, uxn1, uxb1, b1, kptr);
        kt_scan2<<<dim3(B), dim3(512), 0, stream>>>(
            mx1, uxn1, uxb1, w1pk1, whh2g1, b1, hcar1,
            out + (size_t)(NC - 1) * CT * B * H, 256LL, (long long)B * H,
            mx1, uxn1, uxb1, w1pk1, whh2g1, b1, hcar1,
            out + (size_t)(NC - 1) * CT * B * H, 256LL, (long long)B * H,
            kptr, CT, B);
    }
    kt_final<<<dim3(128), blk, 0, stream>>>(hcar, out + (size_t)T * B * H);
}

// Round 7
// 6298.078 us; speedup vs baseline: 2.2098x; 1.2560x over previous
//
#include <hip/hip_runtime.h>
#include <cstdint>
#include <cstddef>

#define MINN 1e-15f
#define EPSA 1e-7f
#define C_L2E 1.44269504088896341f
#define C_LN2 0.69314718055994531f

typedef _Float16 half_t;
typedef _Float16 half2_t __attribute__((ext_vector_type(2)));

#if defined(__has_builtin)
#if __has_builtin(__builtin_amdgcn_update_dpp) && __has_builtin(__builtin_amdgcn_readlane)
#define USE_DPP 1
#endif
#endif

// ---------- fast-math helpers (native, ~1 ulp) ----------
__device__ __forceinline__ float fexp2_(float x) {
#if defined(__has_builtin) && __has_builtin(__builtin_amdgcn_exp2f)
    return __builtin_amdgcn_exp2f(x);
#else
    return exp2f(x);
#endif
}
__device__ __forceinline__ float flog2_(float x) {
#if defined(__has_builtin) && __has_builtin(__builtin_amdgcn_logf)
    return __builtin_amdgcn_logf(x);
#else
    return log2f(x);
#endif
}
__device__ __forceinline__ float frcp_(float x) {
#if defined(__has_builtin) && __has_builtin(__builtin_amdgcn_rcpf)
    return __builtin_amdgcn_rcpf(x);
#else
    return 1.f / x;
#endif
}
__device__ __forceinline__ float tan_k_(float u, float sk, float rsk) {
    float a = fminf(fmaxf(sk * u, -15.f), 15.f);
    float t = fexp2_(a * (2.f * C_L2E));
    return (1.f - 2.f * frcp_(t + 1.f)) * rsk;
}
__device__ __forceinline__ float artan_k_(float u, float sk, float rsk) {
    float a = fminf(fmaxf(sk * u, -1.f + EPSA), 1.f - EPSA);
    return flog2_((1.f + a) * frcp_(1.f - a)) * (0.5f * C_LN2) * rsk;
}
__device__ __forceinline__ float sigm_(float x) {
    return frcp_(1.f + fexp2_(-x * C_L2E));
}
__device__ __forceinline__ float wave_sum(float v) {
#pragma unroll
    for (int off = 32; off; off >>= 1) v += __shfl_xor(v, off, 64);
    return v;
}

// ---------- DPP reduction primitives (VALU pipe, not DS) ----------
#ifdef USE_DPP
template <int CTRL, int RM, int BM>
__device__ __forceinline__ float dppmov_(float x) {
    return __builtin_bit_cast(float,
        __builtin_amdgcn_update_dpp(0, __builtin_bit_cast(int, x), CTRL, RM, BM, false));
}
#endif
// full 64-lane sum; result valid in lane 63 (fallback: all lanes)
__device__ __forceinline__ float wsum63_(float x) {
#ifdef USE_DPP
    x += dppmov_<0x111, 0xf, 0xf>(x);  // row_shr:1
    x += dppmov_<0x112, 0xf, 0xf>(x);  // row_shr:2
    x += dppmov_<0x114, 0xf, 0xe>(x);  // row_shr:4
    x += dppmov_<0x118, 0xf, 0xc>(x);  // row_shr:8  -> lane15 of each row = row sum
    x += dppmov_<0x142, 0xa, 0xf>(x);  // row_bcast:15 -> lane31, lane63 partials
    x += dppmov_<0x143, 0xc, 0xf>(x);  // row_bcast:31 -> lane63 = total
    return x;
#else
    return wave_sum(x);
#endif
}
// 8-lane group prefix sum; result valid in lane 8n+7 (fallback: all lanes)
__device__ __forceinline__ float gsum8_(float x) {
#ifdef USE_DPP
    x += dppmov_<0x111, 0xf, 0xf>(x);
    x += dppmov_<0x112, 0xf, 0xf>(x);
    x += dppmov_<0x114, 0xf, 0xe>(x);
    return x;
#else
    x += __shfl_xor(x, 1, 64);
    x += __shfl_xor(x, 2, 64);
    x += __shfl_xor(x, 4, 64);
    return x;
#endif
}
__device__ __forceinline__ float rdlane_(float x, int l) {
#ifdef USE_DPP
    return __builtin_bit_cast(float,
        __builtin_amdgcn_readlane(__builtin_bit_cast(int, x), l));
#else
    return __shfl(x, l, 64);
#endif
}
// block(512)-wide reduce of N values via DPP + 1 LDS round trip.
// ONE internal barrier; caller alternates redbuf between consecutive uses.
template <int N>
__device__ __forceinline__ void bredX(float* v, float* redbuf, int tid) {
    const int lane = tid & 63, wave = tid >> 6;
#pragma unroll
    for (int n = 0; n < N; ++n) {
        float s = wsum63_(v[n]);
        if (lane == 63) redbuf[n * 8 + wave] = s;
    }
    __syncthreads();
    float part = redbuf[lane & (8 * N - 1)];
    part = gsum8_(part);
#pragma unroll
    for (int n = 0; n < N; ++n) v[n] = rdlane_(part, 8 * n + 7);
}

// f16 pair dot-accumulate
__device__ __forceinline__ float dot2acc(uint32_t w, uint32_t h, float acc) {
#if defined(__has_builtin) && __has_builtin(__builtin_amdgcn_fdot2)
    return __builtin_amdgcn_fdot2(__builtin_bit_cast(half2_t, w),
                                  __builtin_bit_cast(half2_t, h), acc, false);
#else
    half2_t a = __builtin_bit_cast(half2_t, w);
    half2_t b = __builtin_bit_cast(half2_t, h);
    acc = fmaf((float)a[0], (float)b[0], acc);
    return fmaf((float)a[1], (float)b[1], acc);
#endif
}

// ---------- K1: transpose 2 ih weight matrices [768x256] -> [256x768] ----------
__global__ __launch_bounds__(256) void kt_transpose(
    const float* __restrict__ a0, const float* __restrict__ a1,
    float* __restrict__ o0, float* __restrict__ o1) {
    int idx = blockIdx.x * 256 + threadIdx.x;
    int m = idx / 196608, rem = idx % 196608;
    int j = rem >> 8, kk = rem & 255;
    const float* in = (m == 0) ? a0 : a1;
    float* outp     = (m == 0) ? o0 : o1;
    outp[kk * 768 + j] = in[j * 256 + kk];
}

// ---------- prep1: pack stage-1 (W_hr,W_hz) f16 per-thread fragments ----------
// HALF-WAVE pair layout: thread t: lane=t&63, wave=t>>6,
//   p = wave*32 + (lane&31), ph = lane>>5.
__global__ __launch_bounds__(256) void kt_prep1(
    const float* __restrict__ whh0, const float* __restrict__ whh1,
    uint32_t* __restrict__ p0, uint32_t* __restrict__ p1) {
    int idx = blockIdx.x * 256 + threadIdx.x;  // 131072
    int l = idx >> 16, e = idx & 65535;
    int r4 = e >> 11, rem = e & 2047;
    int t = rem >> 2, m = r4 * 4 + (rem & 3);
    int lane = t & 63, wave = t >> 6;
    int p = wave * 32 + (lane & 31), ph = lane >> 5;
    int g = m >> 6, mi = m & 63;
    int row = g ? (512 + p) : p;
    int i = ph * 128 + 2 * mi;
    const float* w = l ? whh1 : whh0;
    half2_t hv;
    hv[0] = (half_t)w[row * 256 + i];
    hv[1] = (half_t)w[row * 256 + i + 1];
    (l ? p1 : p0)[e] = __builtin_bit_cast(uint32_t, hv);
}

// ---------- prep2: pack stage-2 (W_hh_) f16 [i2][j] half2 ----------
__global__ __launch_bounds__(256) void kt_prep2(
    const float* __restrict__ whh0, const float* __restrict__ whh1,
    uint32_t* __restrict__ p0, uint32_t* __restrict__ p1) {
    int idx = blockIdx.x * 256 + threadIdx.x;  // 65536
    int l = idx >> 15, e = idx & 32767;
    int i2 = e >> 8, j = e & 255;
    const float* w = l ? whh1 : whh0;
    half2_t hv;
    hv[0] = (half_t)w[(256 + j) * 256 + 2 * i2];
    hv[1] = (half_t)w[(256 + j) * 256 + 2 * i2 + 1];
    (l ? p1 : p0)[e] = __builtin_bit_cast(uint32_t, hv);
}

// ---------- init / final ----------
__global__ __launch_bounds__(256) void kt_init(
    const float* __restrict__ h0, float* __restrict__ hcar) {
    int i = blockIdx.x * 256 + threadIdx.x;
    hcar[i] = h0[i];
}
__global__ __launch_bounds__(256) void kt_final(
    const float* __restrict__ hcar, float* __restrict__ dst) {
    int i = blockIdx.x * 256 + threadIdx.x;
    dst[i] = hcar[i];
}

// ---------- rowscale / gemm / mscale ----------
__global__ __launch_bounds__(256) void kt_rowscale(
    const float* __restrict__ src, long long strideB,
    float* __restrict__ s_arr, float* __restrict__ ax_arr,
    const float* __restrict__ kptr, int mode) {
    int lane = threadIdx.x & 63;
    int r = blockIdx.x * 4 + (threadIdx.x >> 6);
    float k = kptr[0], sk = sqrtf(-k), rsk = frcp_(sk);
    size_t off = (size_t)(r >> 6) * strideB + (size_t)(r & 63) * 256 + lane * 4;
    float4 v = *(const float4*)&src[off];
    float n2 = wave_sum(v.x * v.x + v.y * v.y + v.z * v.z + v.w * v.w);
    float n = sqrtf(n2);
    float s, xn;
    if (mode == 0) {
        float nrm = fmaxf(n, MINN);
        float tk = tan_k_(nrm, sk, rsk);
        s = tk * frcp_(nrm);
        xn = fmaxf(tk * (n * frcp_(nrm)), MINN);
    } else {
        s = 1.f;
        xn = fmaxf(n, MINN);
    }
    float ax = artan_k_(xn, sk, rsk) * frcp_(xn);
    if (lane == 0) { s_arr[r] = s; ax_arr[r] = ax; }
}

__global__ __launch_bounds__(256) void kt_gemm(
    const float* __restrict__ A, long long strideB,
    const float* __restrict__ s_arr,
    const float* __restrict__ Bt, float* __restrict__ C) {
    __shared__ float As[16][68];
    __shared__ float Bs[16][68];
    __shared__ float sS[64];
    int tid = threadIdx.x;
    int row0 = blockIdx.y * 64, col0 = blockIdx.x * 64;
    if (tid < 64) sS[tid] = s_arr[row0 + tid];
    int ty = tid >> 4, tx = tid & 15;
    int ra = tid >> 2, kq = tid & 3;
    int kb = tid >> 4, cq = tid & 15;
    float acc[4][4] = {};
    __syncthreads();
#pragma unroll 1
    for (int kt = 0; kt < 16; ++kt) {
        int k0 = kt * 16;
        int rc = row0 + ra;
        size_t aoff = (size_t)(rc >> 6) * strideB + (size_t)(rc & 63) * 256 + k0 + kq * 4;
        float4 av = *(const float4*)&A[aoff];
        float sc = sS[ra];
        float4 bv = *(const float4*)&Bt[(size_t)(k0 + kb) * 768 + col0 + cq * 4];
        As[kq * 4 + 0][ra] = av.x * sc;
        As[kq * 4 + 1][ra] = av.y * sc;
        As[kq * 4 + 2][ra] = av.z * sc;
        As[kq * 4 + 3][ra] = av.w * sc;
        *(float4*)&Bs[kb][cq * 4] = bv;
        __syncthreads();
#pragma unroll
        for (int kk = 0; kk < 16; ++kk) {
            float4 a4 = *(const float4*)&As[kk][ty * 4];
            float4 b4 = *(const float4*)&Bs[kk][tx * 4];
            float aa[4] = {a4.x, a4.y, a4.z, a4.w};
            float bb[4] = {b4.x, b4.y, b4.z, b4.w};
#pragma unroll
            for (int i = 0; i < 4; ++i)
#pragma unroll
                for (int j = 0; j < 4; ++j)
                    acc[i][j] = fmaf(aa[i], bb[j], acc[i][j]);
        }
        __syncthreads();
    }
#pragma unroll
    for (int i = 0; i < 4; ++i) {
        size_t row = (size_t)row0 + ty * 4 + i;
        *(float4*)&C[row * 768 + col0 + tx * 4] =
            make_float4(acc[i][0], acc[i][1], acc[i][2], acc[i][3]);
    }
}

// scales mx in place, stores ||Ux|| and (Ux . bias) per (row,gate)
__global__ __launch_bounds__(256) void kt_mscale(
    float* __restrict__ mx, const float* __restrict__ ax_arr,
    float* __restrict__ uxn, float* __restrict__ uxb,
    const float* __restrict__ bias, const float* __restrict__ kptr) {
    int lane = threadIdx.x & 63;
    int p = blockIdx.x * 4 + (threadIdx.x >> 6);
    int r = p / 3;
    int g = p - r * 3;
    float k = kptr[0], sk = sqrtf(-k), rsk = frcp_(sk);
    float* ptr = mx + (size_t)r * 768 + g * 256 + lane * 4;
    float4 v = *(const float4*)ptr;
    float4 b4 = *(const float4*)&bias[g * 256 + lane * 4];
    float n2 = wave_sum(v.x * v.x + v.y * v.y + v.z * v.z + v.w * v.w);
    float vb = wave_sum(v.x * b4.x + v.y * b4.y + v.z * b4.z + v.w * b4.w);
    float nt = sqrtf(n2);
    float mxn = fmaxf(nt, MINN);
    float arg = mxn * ax_arr[r];
    float tk = tan_k_(arg, sk, rsk);
    float f = tk * frcp_(mxn);
    v.x *= f; v.y *= f; v.z *= f; v.w *= f;
    *(float4*)ptr = v;
    if (lane == 0) { uxn[p] = tk * (nt * frcp_(mxn)); uxb[p] = f * vb; }
}

// ---------- K6: persistent-weight scan, dual-role, half-wave pair layout ----------
__global__ __launch_bounds__(512, 1) void kt_scan2(
    const float* __restrict__ Ux_0, const float* __restrict__ uxn_0,
    const float* __restrict__ uxb_0,
    const uint32_t* __restrict__ w1pk_0, const uint32_t* __restrict__ whh2g_0,
    const float* __restrict__ bias_0, float* __restrict__ hcar_0,
    float* __restrict__ out_0, long long sb_0, long long st_0,
    const float* __restrict__ Ux_1, const float* __restrict__ uxn_1,
    const float* __restrict__ uxb_1,
    const uint32_t* __restrict__ w1pk_1, const uint32_t* __restrict__ whh2g_1,
    const float* __restrict__ bias_1, float* __restrict__ hcar_1,
    float* __restrict__ out_1, long long sb_1, long long st_1,
    const float* __restrict__ kptr, int Tc, int nrole0) {
    __shared__ uint4 whhS[8192];       // 128 KiB: W_hh_ f16, [i2-quad][j]
    __shared__ uint32_t hy2S[128];     // hy as 128 half2
    __shared__ uint32_t rh2S[128];     // wx (unscaled rh) as 128 half2
    __shared__ float redbuf[2][64];    // double-buffered reduce scratch

    const int tid = threadIdx.x;
    const int role = (blockIdx.x >= nrole0) ? 1 : 0;
    const int bb = role ? (int)blockIdx.x - nrole0 : (int)blockIdx.x;

    const float* Ux      = role ? Ux_1 : Ux_0;
    const float* uxn     = role ? uxn_1 : uxn_0;
    const float* uxb     = role ? uxb_1 : uxb_0;
    const uint32_t* w1pk = role ? w1pk_1 : w1pk_0;
    const uint32_t* whh2g= role ? whh2g_1 : whh2g_0;
    const float* bias    = role ? bias_1 : bias_0;
    float* hcar          = role ? hcar_1 : hcar_0;
    float* outbase       = role ? out_1 : out_0;
    const long long stride_b = role ? sb_1 : sb_0;
    const long long stride_t = role ? st_1 : st_0;

    const int lane = tid & 63, wave = tid >> 6;
    const int p = wave * 32 + (lane & 31), ph = lane >> 5;
    const float k = kptr[0], sk = sqrtf(-k), rsk = frcp_(sk);

    // stage-2 weights -> LDS
    for (int idx = tid; idx < 32768; idx += 512) {
        uint32_t v = whh2g[idx];
        int i2 = idx >> 8, col = idx & 255;
        ((uint32_t*)whhS)[((i2 >> 2) * 256 + col) * 4 + (i2 & 3)] = v;
    }
    // stage-1 weights -> registers (128 u32 = 256 f16)
    uint32_t w1[128];
    {
        const uint4* wp = (const uint4*)w1pk;  // [32][512] uint4
#pragma unroll
        for (int r4 = 0; r4 < 32; ++r4) {
            uint4 v = wp[r4 * 512 + tid];
            w1[4 * r4 + 0] = v.x; w1[4 * r4 + 1] = v.y;
            w1[4 * r4 + 2] = v.z; w1[4 * r4 + 3] = v.w;
        }
    }

    const float br = bias[p], bh = bias[256 + p], bz = bias[512 + p];
    float h = hcar[bb * 256 + p];
    __syncthreads();  // whhS ready
    float v4[4] = {br * br, bh * bh, bz * bz, h * h};
    bredX<4>(v4, redbuf[0], tid);
    const float bn2r = 0.5f * v4[0], bn2h = 0.5f * v4[1], bn2z = 0.5f * v4[2];
    float S_h2 = 0.5f * v4[3];

    float* myout = outbase + (size_t)bb * stride_b;
    const float* uxpb = Ux + (size_t)bb * Tc * 768;
    const float* unpb = uxn + (size_t)bb * Tc * 3;
    const float* ubpb = uxb + (size_t)bb * Tc * 3;

    // prefetch step 0
    float puxr = uxpb[p], puxh = uxpb[256 + p], puxz = uxpb[512 + p];
    float punr = unpb[0], punh = unpb[1], punz = unpb[2];
    float pubr = ubpb[0], pubh = ubpb[1], pubz = ubpb[2];

    for (int t = 0; t < Tc; ++t) {
        const float uxr = puxr, uxh = puxh, uxz = puxz;
        const float unr = punr, unh = punh, unz = punz;
        const float S_ubr = pubr, S_ubh = pubh, S_ubz = pubz;

        // ---- expmap0(h): scalars from carried S_h2 ----
        float hn = sqrtf(S_h2);
        float nrm = fmaxf(hn, MINN);
        float tk0 = tan_k_(nrm, sk, rsk);
        float chy = tk0 * frcp_(nrm);
        float hy = chy * h;
        float Shy2 = chy * chy * S_h2;
        float xnh = fmaxf(tk0 * (hn * frcp_(nrm)), MINN);
        float axh = artan_k_(xnh, sk, rsk) * frcp_(xnh);
        if (ph == 0) ((half_t*)hy2S)[p] = (half_t)hy;
        __syncthreads();  // B1: hy ready

        // prefetch next step (hidden under matvec + reductions)
        if (t + 1 < Tc) {
            const float* uxp2 = uxpb + (size_t)(t + 1) * 768;
            puxr = uxp2[p]; puxh = uxp2[256 + p]; puxz = uxp2[512 + p];
            const float* unp2 = unpb + (size_t)(t + 1) * 3;
            punr = unp2[0]; punh = unp2[1]; punz = unp2[2];
            const float* ubp2 = ubpb + (size_t)(t + 1) * 3;
            pubr = ubp2[0]; pubh = ubp2[1]; pubz = ubp2[2];
        }

        // ---- stage-1 matvec (r,z), half-split, 2-deep accumulators ----
        float pr0 = 0.f, pr1 = 0.f, pz0 = 0.f, pz1 = 0.f;
        {
            const uint4* hp = (const uint4*)hy2S + ph * 16;
#pragma unroll
            for (int c4 = 0; c4 < 4; ++c4) {
                uint32_t hv[16];
#pragma unroll
                for (int u = 0; u < 4; ++u) {
                    uint4 v = hp[c4 * 4 + u];
                    hv[4 * u + 0] = v.x; hv[4 * u + 1] = v.y;
                    hv[4 * u + 2] = v.z; hv[4 * u + 3] = v.w;
                }
#pragma unroll
                for (int m = 0; m < 16; ++m) {
                    if (c4 < 2) {
                        pr0 = dot2acc(w1[c4 * 16 + m], hv[m], pr0);
                        pz0 = dot2acc(w1[64 + c4 * 16 + m], hv[m], pz0);
                    } else {
                        pr1 = dot2acc(w1[c4 * 16 + m], hv[m], pr1);
                        pz1 = dot2acc(w1[64 + c4 * 16 + m], hv[m], pz1);
                    }
                }
            }
        }
        float pr = pr0 + pr1, pz = pz0 + pz1;
        const float mr = pr + __shfl_xor(pr, 32, 64);
        const float mz = pz + __shfl_xor(pz, 32, 64);

        float vr[8] = {mr * mr, mz * mz, mr * uxr, mz * uxz,
                       mr * br, mz * bz, h * uxh, h * bh};
        bredX<8>(vr, redbuf[0], tid);
        const float S_mr2 = 0.5f * vr[0], S_mz2 = 0.5f * vr[1];
        const float S_mru = 0.5f * vr[2], S_mzu = 0.5f * vr[3];
        const float S_mrb = 0.5f * vr[4], S_mzb = 0.5f * vr[5];
        const float S_huxh = 0.5f * vr[6], S_hbh = 0.5f * vr[7];

        float r_t, z_t;
        {   // --- r gate ---
            float mxn = fmaxf(sqrtf(S_mr2), MINN);
            float tk = tan_k_(mxn * axh, sk, rsk);
            float f = tk * frcp_(mxn);
            float x2 = f * f * S_mr2, y2 = unr * unr, xy = f * S_mru;
            float a = 1.f - 2.f * k * xy - k * y2;
            float bq = 1.f + k * x2;
            float rd = frcp_(fmaxf(1.f - 2.f * k * xy + k * k * x2 * y2, MINN));
            float c1 = (a * f * mr + bq * uxr) * rd;
            float Sc12 = (a * a * x2 + 2.f * a * bq * xy + bq * bq * y2) * (rd * rd);
            float Sc1b = (a * f * S_mrb + bq * S_ubr) * rd;
            float g = 1.f - 2.f * k * Sc1b - k * bn2r;
            float dl = 1.f + k * Sc12;
            float re = frcp_(fmaxf(1.f - 2.f * k * Sc1b + k * k * Sc12 * bn2r, MINN));
            float c2 = (g * c1 + dl * br) * re;
            float Sc22 = (g * g * Sc12 + 2.f * g * dl * Sc1b + dl * dl * bn2r) * (re * re);
            float yn = fmaxf(sqrtf(Sc22), MINN);
            float lr = artan_k_(yn, sk, rsk) * frcp_(yn) * c2;
            r_t = sigm_(lr);
        }
        {   // --- z gate ---
            float mxn = fmaxf(sqrtf(S_mz2), MINN);
            float tk = tan_k_(mxn * axh, sk, rsk);
            float f = tk * frcp_(mxn);
            float x2 = f * f * S_mz2, y2 = unz * unz, xy = f * S_mzu;
            float a = 1.f - 2.f * k * xy - k * y2;
            float bq = 1.f + k * x2;
            float rd = frcp_(fmaxf(1.f - 2.f * k * xy + k * k * x2 * y2, MINN));
            float c1 = (a * f * mz + bq * uxz) * rd;
            float Sc12 = (a * a * x2 + 2.f * a * bq * xy + bq * bq * y2) * (rd * rd);
            float Sc1b = (a * f * S_mzb + bq * S_ubz) * rd;
            float g = 1.f - 2.f * k * Sc1b - k * bn2z;
            float dl = 1.f + k * Sc12;
            float re = frcp_(fmaxf(1.f - 2.f * k * Sc1b + k * k * Sc12 * bn2z, MINN));
            float c2 = (g * c1 + dl * bz) * re;
            float Sc22 = (g * g * Sc12 + 2.f * g * dl * Sc1b + dl * dl * bn2z) * (re * re);
            float yn = fmaxf(sqrtf(Sc22), MINN);
            float lz = artan_k_(yn, sk, rsk) * frcp_(yn) * c2;
            z_t = sigm_(lz);
        }

        // ---- rh: publish UNSCALED wx; merge S_wx2 reduction into same barrier ----
        float wx = r_t * hy;
        if (ph == 0) ((half_t*)rh2S)[p] = (half_t)wx;
        {
            float s1v = wsum63_(wx * wx);
            if (lane == 63) redbuf[1][wave] = s1v;
        }
        __syncthreads();  // B_B: rh/wx ready + v1 partials ready

        float part1 = gsum8_(redbuf[1][lane & 7]);
        const float S_wx2 = 0.5f * rdlane_(part1, 7);
        float wxt = sqrtf(S_wx2);
        float wxn = fmaxf(wxt, MINN);
        float tkw = tan_k_(wxn * axh, sk, rsk);
        float fw = tkw * frcp_(wxn);      // rh = fw * wx (fw is block scalar)
        float rhn = tkw * (wxt * frcp_(wxn));

        // ---- stage-2 matvec (h gate), half-split, 2-deep accumulators ----
        float q0 = 0.f, q1 = 0.f;
        {
            const uint4* rp = (const uint4*)rh2S + ph * 16;
#pragma unroll
            for (int u = 0; u < 16; ++u) {
                uint4 wv = whhS[(ph * 16 + u) * 256 + p];
                uint4 rv = rp[u];
                if (u < 8) {
                    q0 = dot2acc(wv.x, rv.x, q0);
                    q0 = dot2acc(wv.y, rv.y, q0);
                    q0 = dot2acc(wv.z, rv.z, q0);
                    q0 = dot2acc(wv.w, rv.w, q0);
                } else {
                    q1 = dot2acc(wv.x, rv.x, q1);
                    q1 = dot2acc(wv.y, rv.y, q1);
                    q1 = dot2acc(wv.z, rv.z, q1);
                    q1 = dot2acc(wv.w, rv.w, q1);
                }
            }
        }
        float qq = q0 + q1;
        const float mh = fw * (qq + __shfl_xor(qq, 32, 64));

        float v4b[4] = {mh * mh, mh * uxh, mh * bh, hy * mh};
        bredX<4>(v4b, redbuf[0], tid);
        const float S_mh2 = 0.5f * v4b[0], S_mhu = 0.5f * v4b[1];
        const float S_mhb = 0.5f * v4b[2], S_hymh = 0.5f * v4b[3];

        float wz, Sdelta2;
        {
            float xnrh = fmaxf(rhn, MINN);
            float axrh = artan_k_(xnrh, sk, rsk) * frcp_(xnrh);
            float mxn = fmaxf(sqrtf(S_mh2), MINN);
            float tk = tan_k_(mxn * axrh, sk, rsk);
            float f = tk * frcp_(mxn);
            float x2 = f * f * S_mh2, y2 = unh * unh, xy = f * S_mhu;
            float a = 1.f - 2.f * k * xy - k * y2;
            float bq = 1.f + k * x2;
            float rd = frcp_(fmaxf(1.f - 2.f * k * xy + k * k * x2 * y2, MINN));
            float c1 = (a * f * mh + bq * uxh) * rd;
            float Sc12 = (a * a * x2 + 2.f * a * bq * xy + bq * bq * y2) * (rd * rd);
            float Sc1b = (a * f * S_mhb + bq * S_ubh) * rd;
            float S_hyc1 = (a * f * S_hymh + bq * chy * S_huxh) * rd;
            float g = 1.f - 2.f * k * Sc1b - k * bn2h;
            float dl = 1.f + k * Sc12;
            float re = frcp_(fmaxf(1.f - 2.f * k * Sc1b + k * k * Sc12 * bn2h, MINN));
            float htl = (g * c1 + dl * bh) * re;
            float Shtl2 = (g * g * Sc12 + 2.f * g * dl * Sc1b + dl * dl * bn2h) * (re * re);
            float S_hyhtl = (g * S_hyc1 + dl * chy * S_hbh) * re;
            // delta = mobius_add(-hy, htl): xy_d = -S_hyhtl
            float ad = 1.f + 2.f * k * S_hyhtl - k * Shtl2;
            float bd = 1.f + k * Shy2;
            float rdd = frcp_(fmaxf(1.f + 2.f * k * S_hyhtl + k * k * Shy2 * Shtl2, MINN));
            float delta = (ad * (-hy) + bd * htl) * rdd;
            Sdelta2 = (ad * ad * Shy2 - 2.f * ad * bd * S_hyhtl + bd * bd * Shtl2) * (rdd * rdd);
            wz = z_t * delta;
        }
        float v2[2] = {wz * wz, hy * wz};
        bredX<2>(v2, redbuf[1], tid);
        const float S_wz2 = 0.5f * v2[0], S_hywz = 0.5f * v2[1];

        {
            float dnc = fmaxf(sqrtf(Sdelta2), MINN);
            float axd = artan_k_(dnc, sk, rsk) * frcp_(dnc);
            float wzt = sqrtf(S_wz2);
            float wznc = fmaxf(wzt, MINN);
            float tkzd = tan_k_(wznc * axd, sk, rsk);
            float fz = tkzd * frcp_(wznc);
            float zd = fz * wz;
            float zdn2 = fz * fz * S_wz2;
            float S_hyzd = fz * S_hywz;
            float an = 1.f - 2.f * k * S_hyzd - k * zdn2;
            float bn_ = 1.f + k * Shy2;
            float rdn = frcp_(fmaxf(1.f - 2.f * k * S_hyzd + k * k * Shy2 * zdn2, MINN));
            float hnew = (an * hy + bn_ * zd) * rdn;
            float Shnew2 = (an * an * Shy2 + 2.f * an * bn_ * S_hyzd + bn_ * bn_ * zdn2) * (rdn * rdn);
            float yn = fmaxf(sqrtf(Shnew2), MINN);
            float ayn = artan_k_(yn, sk, rsk) * frcp_(yn);
            float outv = ayn * hnew;
            if (ph == 0) myout[(size_t)t * stride_t + p] = outv;
            h = outv;
            S_h2 = ayn * ayn * Shnew2;  // carried, no reduction needed
        }
    }
    if (ph == 0) hcar[bb * 256 + p] = h;
}

// ---------- host launcher ----------
extern "C" void kernel_launch(void* const* d_in, const int* in_sizes, int n_in,
                              void* d_out, int out_size, void* d_ws, size_t ws_size,
                              hipStream_t stream) {
    const float* x    = (const float*)d_in[0];
    const float* kptr = (const float*)d_in[1];
    const float* h0   = (const float*)d_in[2];
    const float* wih0 = (const float*)d_in[3];
    const float* whh0 = (const float*)d_in[4];
    const float* b0   = (const float*)d_in[5];
    const float* wih1 = (const float*)d_in[6];
    const float* whh1 = (const float*)d_in[7];
    const float* b1   = (const float*)d_in[8];
    float* out = (float*)d_out;
    float* ws  = (float*)d_ws;

    const int B = 64, T = 1024, H = 256;
    const int CT = 64, NC = 16;
    const int RC = B * CT;  // 4096

    float* wt_ih0 = ws;
    float* wt_ih1 = wt_ih0 + 196608;
    uint32_t* w1pk0  = (uint32_t*)(wt_ih1 + 196608);
    uint32_t* w1pk1  = w1pk0 + 65536;
    uint32_t* whh2g0 = w1pk1 + 65536;
    uint32_t* whh2g1 = whh2g0 + 32768;
    float* hcar  = (float*)(whh2g1 + 32768);
    float* s0    = hcar + 32768;
    float* ax0   = s0 + RC;
    float* s1    = ax0 + RC;
    float* ax1   = s1 + RC;
    float* uxn0  = ax1 + RC;
    float* uxn1  = uxn0 + 3 * RC;
    float* uxb0  = uxn1 + 3 * RC;
    float* uxb1  = uxb0 + 3 * RC;
    float* out0c = uxb1 + 3 * RC;
    float* mx0   = out0c + (size_t)RC * H;
    float* mx1   = mx0 + (size_t)RC * 768;

    float* hcar0 = hcar;
    float* hcar1 = hcar + (size_t)B * H;

    dim3 blk(256);
    kt_transpose<<<dim3(1536), blk, 0, stream>>>(wih0, wih1, wt_ih0, wt_ih1);
    kt_prep1<<<dim3(512), blk, 0, stream>>>(whh0, whh1, w1pk0, w1pk1);
    kt_prep2<<<dim3(256), blk, 0, stream>>>(whh0, whh1, whh2g0, whh2g1);
    kt_init<<<dim3(128), blk, 0, stream>>>(h0, hcar);

    const long long sbx = (long long)T * 256;
    const long long sbc = (long long)CT * 256;

    // ---- prologue: layer 0, chunk 0 ----
    {
        const float* xc = x;
        kt_rowscale<<<dim3(RC / 4), blk, 0, stream>>>(xc, sbx, s0, ax0, kptr, 0);
        kt_gemm<<<dim3(12, RC / 64), blk, 0, stream>>>(xc, sbx, s0, wt_ih0, mx0);
        kt_mscale<<<dim3(RC * 3 / 4), blk, 0, stream>>>(mx0, ax0, uxn0, uxb0, b0, kptr);
        kt_scan2<<<dim3(B), dim3(512), 0, stream>>>(
            mx0, uxn0, uxb0, w1pk0, whh2g0, b0, hcar0, out0c, sbc, 256LL,
            mx0, uxn0, uxb0, w1pk0, whh2g0, b0, hcar0, out0c, sbc, 256LL,
            kptr, CT, B);
    }
    // ---- steady state: dual scans (L0 chunk c || L1 chunk c-1) ----
    for (int c = 1; c < NC; ++c) {
        const float* xc = x + (size_t)c * CT * 256;
        kt_rowscale<<<dim3(RC / 4), blk, 0, stream>>>(xc, sbx, s0, ax0, kptr, 0);
        kt_gemm<<<dim3(12, RC / 64), blk, 0, stream>>>(xc, sbx, s0, wt_ih0, mx0);
        kt_mscale<<<dim3(RC * 3 / 4), blk, 0, stream>>>(mx0, ax0, uxn0, uxb0, b0, kptr);
        kt_rowscale<<<dim3(RC / 4), blk, 0, stream>>>(out0c, sbc, s1, ax1, kptr, 1);
        kt_gemm<<<dim3(12, RC / 64), blk, 0, stream>>>(out0c, sbc, s1, wt_ih1, mx1);
        kt_mscale<<<dim3(RC * 3 / 4), blk, 0, stream>>>(mx1, ax1, uxn1, uxb1, b1, kptr);
        kt_scan2<<<dim3(2 * B), dim3(512), 0, stream>>>(
            mx0, uxn0, uxb0, w1pk0, whh2g0, b0, hcar0, out0c, sbc, 256LL,
            mx1, uxn1, uxb1, w1pk1, whh2g1, b1, hcar1,
            out + (size_t)(c - 1) * CT * B * H, 256LL, (long long)B * H,
            kptr, CT, B);
    }
    // ---- epilogue: layer 1, chunk NC-1 ----
    {
        kt_rowscale<<<dim3(RC / 4), blk, 0, stream>>>(out0c, sbc, s1, ax1, kptr, 1);
        kt_gemm<<<dim3(12, RC / 64), blk, 0, stream>>>(out0c, sbc, s1, wt_ih1, mx1);
        kt_mscale<<<dim3(RC * 3 / 4), blk, 0, stream>>>(mx1, ax1, uxn1, uxb1, b1, kptr);
        kt_scan2<<<dim3(B), dim3(512), 0, stream>>>(
            mx1, uxn1, uxb1, w1pk1, whh2g1, b1, hcar1,
            out + (size_t)(NC - 1) * CT * B * H, 256LL, (long long)B * H,
            mx1, uxn1, uxb1, w1pk1, whh2g1, b1, hcar1,
            out + (size_t)(NC - 1) * CT * B * H, 256LL, (long long)B * H,
            kptr, CT, B);
    }
    kt_final<<<dim3(128), blk, 0, stream>>>(hcar, out + (size_t)T * B * H);
}